// Round 1
// baseline (78860.114 us; speedup 1.0000x reference)
//
#include <hip/hip_runtime.h>

#define T_STEPS 512
#define BATCH 64
#define DIM 1024
#define HID 1024
#define NLAYER 2

typedef __attribute__((ext_vector_type(8))) short bf16x8;
typedef __attribute__((ext_vector_type(4))) float f32x4;
typedef unsigned short u16;
typedef unsigned int u32;

__device__ inline float bf2f(u16 u){ u32 v=((u32)u)<<16; float f; __builtin_memcpy(&f,&v,4); return f; }
__device__ inline u16 f2bf(float f){ u32 u; __builtin_memcpy(&u,&f,4); u = (u + 0x7fffu + ((u>>16)&1u))>>16; return (u16)u; }
__device__ inline float sigm(float x){ return 1.f/(1.f+__expf(-x)); }

// ---------------- fp32 -> bf16 cast (x into seq buffer) ----------------
__global__ void cast_f2bf(const float* __restrict__ src, u16* __restrict__ dst, int n4){
  int i = blockIdx.x*blockDim.x + threadIdx.x;
  int stride = gridDim.x*blockDim.x;
  for(; i<n4; i+=stride){
    float4 v = ((const float4*)src)[i];
    ushort4 o; o.x=f2bf(v.x); o.y=f2bf(v.y); o.z=f2bf(v.z); o.w=f2bf(v.w);
    ((ushort4*)dst)[i]=o;
  }
}

// ---------------- transpose + cast: src fp32 [R][C] -> dst bf16 [C][R] ----------------
__global__ void transpose_cast(const float* __restrict__ src, u16* __restrict__ dst, int R, int C){
  __shared__ float tile[32][33];
  int c0 = blockIdx.x*32, r0 = blockIdx.y*32;
  int tx = threadIdx.x, ty = threadIdx.y;
  for(int i=ty;i<32;i+=8) tile[i][tx] = src[(size_t)(r0+i)*C + c0+tx];
  __syncthreads();
  for(int i=ty;i<32;i+=8) dst[(size_t)(c0+i)*R + r0+tx] = f2bf(tile[tx][i]);
}

// ---------------- bf16 GEMM: C[M][N] = A[M][K] @ Bt[N][K]^T + bias[N] ----------------
__launch_bounds__(256)
__global__ void gemm_bt(const u16* __restrict__ A, const u16* __restrict__ Bt,
                        const float* __restrict__ bias, u16* __restrict__ Cmat,
                        int M, int N, int K){
  __shared__ __align__(16) u16 As[128*32];
  __shared__ __align__(16) u16 Bs[128*32];
  const int tid=threadIdx.x, lane=tid&63, wave=tid>>6;
  const size_t m0 = (size_t)blockIdx.y*128, n0=(size_t)blockIdx.x*128;
  const int wr=wave>>1, wc=wave&1, fr=lane&15, fq=lane>>4;
  f32x4 acc[4][4];
  for(int m=0;m<4;m++) for(int n=0;n<4;n++) acc[m][n]=(f32x4){0.f,0.f,0.f,0.f};
  const int nk = K>>5;
  for(int kt=0;kt<nk;kt++){
    __syncthreads();
    for(int j=0;j<2;j++){
      int c = tid + j*256; int row=c>>2; int ko=(c&3)*8;
      *(int4*)&As[row*32+ko] = *(const int4*)&A[(m0+row)*K + kt*32+ko];
      *(int4*)&Bs[row*32+ko] = *(const int4*)&Bt[(n0+row)*K + kt*32+ko];
    }
    __syncthreads();
    bf16x8 af[4], bfv[4];
    for(int m=0;m<4;m++) af[m]=*(const bf16x8*)&As[(wr*64+m*16+fr)*32 + fq*8];
    for(int n=0;n<4;n++) bfv[n]=*(const bf16x8*)&Bs[(wc*64+n*16+fr)*32 + fq*8];
    for(int m=0;m<4;m++)
      for(int n=0;n<4;n++)
        acc[m][n]=__builtin_amdgcn_mfma_f32_16x16x32_bf16(af[m],bfv[n],acc[m][n],0,0,0);
  }
  for(int n=0;n<4;n++){
    size_t colg = n0 + wc*64+n*16+fr;
    float bv = bias[colg];
    for(int m=0;m<4;m++){
      for(int r=0;r<4;r++){
        size_t rowg = m0 + wr*64+m*16+fq*4+r;
        Cmat[rowg*N + colg] = f2bf(acc[m][n][r]+bv);
      }
    }
  }
}

// ---------------- grid barrier (monotonic counter, 64 blocks) ----------------
__device__ inline void grid_barrier(u32* cnt, u32 target){
  __threadfence();
  __syncthreads();
  if(threadIdx.x==0){
    __hip_atomic_fetch_add(cnt,1u,__ATOMIC_RELEASE,__HIP_MEMORY_SCOPE_AGENT);
    while(__hip_atomic_load(cnt,__ATOMIC_ACQUIRE,__HIP_MEMORY_SCOPE_AGENT) < target)
      __builtin_amdgcn_s_sleep(1);
  }
  __syncthreads();
  __threadfence();
}

// ---------------- persistent recurrent kernel: one layer, T steps ----------------
// 64 blocks x 256 threads. Block cj owns cols [16cj,16cj+16) of m/g/c/h and the
// corresponding (i,o,f) column triple of gp. Wave w owns batch rows [16w,16w+16).
__launch_bounds__(256)
__global__ void mlstm_rec(const u16* __restrict__ xp,
   const u16* __restrict__ Wmh_t, const u16* __restrict__ Whh_t, const u16* __restrict__ Wg_t,
   const float* __restrict__ bmh, const float* __restrict__ bhh, const float* __restrict__ bg,
   u16* h_buf, float* c_buf, u16* m_buf, u16* g_buf,
   u16* seq_bf, float* seq_f32, float* hn, float* cn, u32* cnt, int is_first)
{
  const int tid=threadIdx.x, lane=tid&63, wave=tid>>6;
  const int colbase = blockIdx.x*16;
  const int rowbase = wave*16;
  const int fr=lane&15, fq=lane>>4;
  const int col = colbase+fr;
  const u32 a_off = (u32)(rowbase+fr)*HID + fq*8;   // activation fragment base
  const u32 w_off = (u32)(colbase+fr)*HID + fq*8;   // weight fragment base

  float c_reg[4], h4[4], g4[4];
  if(is_first){ for(int r=0;r<4;r++) c_reg[r]=0.f; }
  else { for(int r=0;r<4;r++) c_reg[r]=c_buf[(size_t)(rowbase+fq*4+r)*HID+col]; }
  for(int r=0;r<4;r++) h4[r]=0.f;

  const float bmh_c=bmh[col], bhh_c=bhh[col];
  const float bg_i=bg[col], bg_o=bg[HID+col], bg_f=bg[2*HID+col];
  u32 bar=0;

  for(int t=0;t<T_STEPS;t++){
    const u16* xpt = xp + (size_t)t*BATCH*5*HID;
    // ---- Stage A: mpre = h @ Wmh ; m = xmi * (mpre + bmh)
    f32x4 a0={0.f,0.f,0.f,0.f}, a1={0.f,0.f,0.f,0.f};
    #pragma unroll 4
    for(int kt=0;kt<32;kt+=2){
      bf16x8 av0=*(const bf16x8*)(h_buf + a_off + kt*32);
      bf16x8 wv0=*(const bf16x8*)(Wmh_t + w_off + kt*32);
      bf16x8 av1=*(const bf16x8*)(h_buf + a_off + kt*32+32);
      bf16x8 wv1=*(const bf16x8*)(Wmh_t + w_off + kt*32+32);
      a0=__builtin_amdgcn_mfma_f32_16x16x32_bf16(av0,wv0,a0,0,0,0);
      a1=__builtin_amdgcn_mfma_f32_16x16x32_bf16(av1,wv1,a1,0,0,0);
    }
    for(int r=0;r<4;r++){
      int row=rowbase+fq*4+r;
      float xmi = bf2f(xpt[(size_t)row*5*HID + col]);
      float m = xmi*(a0[r]+a1[r]+bmh_c);
      m_buf[(size_t)row*HID+col]=f2bf(m);
    }
    bar+=64; grid_barrier(cnt,bar);
    // ---- Stage B: g = xhi + m @ Whh + bhh
    a0=(f32x4){0.f,0.f,0.f,0.f}; a1=(f32x4){0.f,0.f,0.f,0.f};
    #pragma unroll 4
    for(int kt=0;kt<32;kt+=2){
      bf16x8 av0=*(const bf16x8*)(m_buf + a_off + kt*32);
      bf16x8 wv0=*(const bf16x8*)(Whh_t + w_off + kt*32);
      bf16x8 av1=*(const bf16x8*)(m_buf + a_off + kt*32+32);
      bf16x8 wv1=*(const bf16x8*)(Whh_t + w_off + kt*32+32);
      a0=__builtin_amdgcn_mfma_f32_16x16x32_bf16(av0,wv0,a0,0,0,0);
      a1=__builtin_amdgcn_mfma_f32_16x16x32_bf16(av1,wv1,a1,0,0,0);
    }
    for(int r=0;r<4;r++){
      int row=rowbase+fq*4+r;
      float xhi = bf2f(xpt[(size_t)row*5*HID + HID + col]);
      g4[r]=a0[r]+a1[r]+bhh_c+xhi;
      g_buf[(size_t)row*HID+col]=f2bf(g4[r]);
    }
    bar+=64; grid_barrier(cnt,bar);
    // ---- Stage C: gp = g @ Wg (i,o,f triples) ; gates ; state update
    f32x4 ai={0.f,0.f,0.f,0.f},ao={0.f,0.f,0.f,0.f},af={0.f,0.f,0.f,0.f};
    #pragma unroll 2
    for(int kt=0;kt<32;kt++){
      bf16x8 gv=*(const bf16x8*)(g_buf + a_off + kt*32);
      bf16x8 wi=*(const bf16x8*)(Wg_t + w_off + kt*32);
      bf16x8 wo=*(const bf16x8*)(Wg_t + w_off + (size_t)HID*HID + kt*32);
      bf16x8 wf=*(const bf16x8*)(Wg_t + w_off + (size_t)2*HID*HID + kt*32);
      ai=__builtin_amdgcn_mfma_f32_16x16x32_bf16(gv,wi,ai,0,0,0);
      ao=__builtin_amdgcn_mfma_f32_16x16x32_bf16(gv,wo,ao,0,0,0);
      af=__builtin_amdgcn_mfma_f32_16x16x32_bf16(gv,wf,af,0,0,0);
    }
    for(int r=0;r<4;r++){
      int row=rowbase+fq*4+r;
      float xii=bf2f(xpt[(size_t)row*5*HID + 2*HID+col]);
      float xoi=bf2f(xpt[(size_t)row*5*HID + 3*HID+col]);
      float xfi=bf2f(xpt[(size_t)row*5*HID + 4*HID+col]);
      float iv=sigm(ai[r]+bg_i+xii);
      float ov=sigm(ao[r]+bg_o+xoi);
      float fv=sigm(af[r]+bg_f+xfi);
      c_reg[r]=fv*c_reg[r]+iv*tanhf(g4[r]);
      h4[r]=tanhf(c_reg[r])*ov;
      h_buf[(size_t)row*HID+col]=f2bf(h4[r]);
      if(seq_bf) seq_bf[(size_t)t*BATCH*HID + (size_t)row*HID+col]=f2bf(h4[r]);
      else       seq_f32[(size_t)t*BATCH*HID + (size_t)row*HID+col]=h4[r];
    }
    bar+=64; grid_barrier(cnt,bar);
  }
  for(int r=0;r<4;r++){
    int row=rowbase+fq*4+r;
    hn[(size_t)row*HID+col]=h4[r];
    cn[(size_t)row*HID+col]=c_reg[r];
    if(is_first) c_buf[(size_t)row*HID+col]=c_reg[r];
  }
}

extern "C" void kernel_launch(void* const* d_in, const int* in_sizes, int n_in,
                              void* d_out, int out_size, void* d_ws, size_t ws_size,
                              hipStream_t stream){
  const float* x   = (const float*)d_in[0];
  const float* Wx  = (const float*)d_in[1];
  const float* bx  = (const float*)d_in[2];
  const float* Wmh = (const float*)d_in[3];
  const float* bmh = (const float*)d_in[4];
  const float* Whh = (const float*)d_in[5];
  const float* bhh = (const float*)d_in[6];
  const float* Wg  = (const float*)d_in[7];
  const float* bg  = (const float*)d_in[8];
  float* out = (float*)d_out;
  char* ws = (char*)d_ws;

  size_t off=0;
  auto alloc=[&](size_t b){ size_t o=off; off += (b+255)&~(size_t)255; return o; };
  size_t xp_off  = alloc((size_t)T_STEPS*BATCH*5*HID*2);   // 335.5 MB
  size_t seq_off = alloc((size_t)T_STEPS*BATCH*HID*2);     // 67 MB
  size_t wx_off  = alloc((size_t)NLAYER*5*HID*DIM*2);      // 21 MB
  size_t wmh_off = alloc((size_t)NLAYER*HID*HID*2);
  size_t whh_off = alloc((size_t)NLAYER*HID*HID*2);
  size_t wg_off  = alloc((size_t)NLAYER*3*HID*HID*2);
  size_t h_off   = alloc((size_t)BATCH*HID*2);
  size_t m_off   = alloc((size_t)BATCH*HID*2);
  size_t g_off   = alloc((size_t)BATCH*HID*2);
  size_t c_off   = alloc((size_t)BATCH*HID*4);
  size_t cnt_off = alloc(256);
  (void)ws_size;

  u16* xp_p = (u16*)(ws+xp_off);
  u16* seq_p= (u16*)(ws+seq_off);
  u16* wx_p = (u16*)(ws+wx_off);
  u16* wmh_p= (u16*)(ws+wmh_off);
  u16* whh_p= (u16*)(ws+whh_off);
  u16* wg_p = (u16*)(ws+wg_off);
  u16* h_p  = (u16*)(ws+h_off);
  u16* m_p  = (u16*)(ws+m_off);
  u16* g_p  = (u16*)(ws+g_off);
  float* c_p= (float*)(ws+c_off);
  u32* cnt_p= (u32*)(ws+cnt_off);

  hipMemsetAsync(h_p, 0, (size_t)BATCH*HID*2, stream);
  hipMemsetAsync(cnt_p, 0, 256, stream);

  cast_f2bf<<<4096,256,0,stream>>>(x, seq_p, T_STEPS*BATCH*DIM/4);

  for(int l=0;l<NLAYER;l++){
    transpose_cast<<<dim3(5*HID/32, DIM/32), dim3(32,8),0,stream>>>(
        Wx + (size_t)l*DIM*5*HID, wx_p + (size_t)l*5*HID*DIM, DIM, 5*HID);
    transpose_cast<<<dim3(HID/32, HID/32), dim3(32,8),0,stream>>>(
        Wmh + (size_t)l*HID*HID, wmh_p + (size_t)l*HID*HID, HID, HID);
    transpose_cast<<<dim3(HID/32, HID/32), dim3(32,8),0,stream>>>(
        Whh + (size_t)l*HID*HID, whh_p + (size_t)l*HID*HID, HID, HID);
    transpose_cast<<<dim3(3*HID/32, HID/32), dim3(32,8),0,stream>>>(
        Wg + (size_t)l*HID*3*HID, wg_p + (size_t)l*3*HID*HID, HID, 3*HID);
  }

  float* seq_out_f32 = out;                                  // [T,B,H]
  float* hn_out = out + (size_t)T_STEPS*BATCH*HID;           // [L,B,H]
  float* cn_out = hn_out + (size_t)NLAYER*BATCH*HID;         // [L,B,H]

  for(int l=0;l<NLAYER;l++){
    gemm_bt<<<dim3(5*HID/128, T_STEPS*BATCH/128),256,0,stream>>>(
        seq_p, wx_p+(size_t)l*5*HID*DIM, bx + (size_t)l*5*HID, xp_p,
        T_STEPS*BATCH, 5*HID, DIM);

    const u16* xp_c = xp_p;
    const u16* xw_m = wmh_p + (size_t)l*HID*HID;
    const u16* xw_h = whh_p + (size_t)l*HID*HID;
    const u16* xw_g = wg_p + (size_t)l*3*HID*HID;
    const float* bmh_l = bmh + (size_t)l*HID;
    const float* bhh_l = bhh + (size_t)l*HID;
    const float* bg_l  = bg + (size_t)l*3*HID;
    u16* seqbf = (l==0)? seq_p : (u16*)nullptr;
    float* seqf = (l==0)? (float*)nullptr : seq_out_f32;
    float* hn_l = hn_out + (size_t)l*BATCH*HID;
    float* cn_l = cn_out + (size_t)l*BATCH*HID;
    u32* cnt_l = cnt_p + l*16;
    int is_first = (l==0)?1:0;
    void* args[] = { (void*)&xp_c, (void*)&xw_m, (void*)&xw_h, (void*)&xw_g,
      (void*)&bmh_l,(void*)&bhh_l,(void*)&bg_l,
      (void*)&h_p,(void*)&c_p,(void*)&m_p,(void*)&g_p,
      (void*)&seqbf,(void*)&seqf,(void*)&hn_l,(void*)&cn_l,(void*)&cnt_l,(void*)&is_first };
    hipLaunchCooperativeKernel((void*)mlstm_rec, dim3(64), dim3(256), args, 0, stream);
  }
}

// Round 4
// 54997.308 us; speedup vs baseline: 1.4339x; 1.4339x over previous
//
#include <hip/hip_runtime.h>

#define T_STEPS 512
#define BATCH 64
#define DIM 1024
#define HID 1024
#define NLAYER 2

typedef __attribute__((ext_vector_type(8))) short bf16x8;
typedef __attribute__((ext_vector_type(4))) float f32x4;
typedef unsigned short u16;
typedef unsigned int u32;

__device__ inline float bf2f(u16 u){ u32 v=((u32)u)<<16; float f; __builtin_memcpy(&f,&v,4); return f; }
__device__ inline u16 f2bf(float f){ u32 u; __builtin_memcpy(&u,&f,4); u = (u + 0x7fffu + ((u>>16)&1u))>>16; return (u16)u; }
__device__ inline float sigm(float x){ return 1.f/(1.f+__expf(-x)); }

// ---------------- fp32 -> bf16 cast ----------------
__global__ void cast_f2bf(const float* __restrict__ src, u16* __restrict__ dst, int n4){
  int i = blockIdx.x*blockDim.x + threadIdx.x;
  int stride = gridDim.x*blockDim.x;
  for(; i<n4; i+=stride){
    float4 v = ((const float4*)src)[i];
    ushort4 o; o.x=f2bf(v.x); o.y=f2bf(v.y); o.z=f2bf(v.z); o.w=f2bf(v.w);
    ((ushort4*)dst)[i]=o;
  }
}

// ---------------- transpose + cast: src fp32 [R][C] -> dst bf16 [C][R] ----------------
__global__ void transpose_cast(const float* __restrict__ src, u16* __restrict__ dst, int R, int C){
  __shared__ float tile[32][33];
  int c0 = blockIdx.x*32, r0 = blockIdx.y*32;
  int tx = threadIdx.x, ty = threadIdx.y;
  for(int i=ty;i<32;i+=8) tile[i][tx] = src[(size_t)(r0+i)*C + c0+tx];
  __syncthreads();
  for(int i=ty;i<32;i+=8) dst[(size_t)(c0+i)*R + r0+tx] = f2bf(tile[tx][i]);
}

// ---------------- bias2 = bhh @ Wg + bg  (per layer, [3H]) ----------------
__global__ void bias2_kernel(const u16* __restrict__ Wg_t, const float* __restrict__ bhh,
                             const float* __restrict__ bg, float* __restrict__ bias2){
  int w = (blockIdx.x*blockDim.x + threadIdx.x)>>6;
  int lane = threadIdx.x&63;
  if(w >= 3*HID) return;
  float s=0.f;
  for(int j=lane;j<HID;j+=64) s += bf2f(Wg_t[(size_t)w*HID + j]) * bhh[j];
  for(int off=32;off;off>>=1) s += __shfl_down(s, off);
  if(lane==0) bias2[w] = s + bg[w];
}

// ---------------- bf16 GEMM: C[M][N] = A[M][K] @ Bt[N][K]^T + bias[N] ----------------
// MODE 0: write Cmat[row*N+col]
// MODE 1: split columns into 5 planes of width HID: planes[p][row*HID+pc]
// MODE 2: N=3H; val += bias + planes[2+p][row*HID+pc]; write back to planes[2+p]
template<int MODE>
__launch_bounds__(256)
__global__ void gemm_bt(const u16* __restrict__ A, const u16* __restrict__ Bt,
                        const float* __restrict__ bias, u16* __restrict__ Cmat,
                        int M, int N, int K, u16* planes, size_t PS){
  __shared__ __align__(16) u16 As[128*32];
  __shared__ __align__(16) u16 Bs[128*32];
  const int tid=threadIdx.x, lane=tid&63, wave=tid>>6;
  const size_t m0 = (size_t)blockIdx.y*128, n0=(size_t)blockIdx.x*128;
  const int wr=wave>>1, wc=wave&1, fr=lane&15, fq=lane>>4;
  f32x4 acc[4][4];
  for(int m=0;m<4;m++) for(int n=0;n<4;n++) acc[m][n]=(f32x4){0.f,0.f,0.f,0.f};
  const int nk = K>>5;
  for(int kt=0;kt<nk;kt++){
    __syncthreads();
    for(int j=0;j<2;j++){
      int c = tid + j*256; int row=c>>2; int ko=(c&3)*8;
      *(int4*)&As[row*32+ko] = *(const int4*)&A[(m0+row)*K + kt*32+ko];
      *(int4*)&Bs[row*32+ko] = *(const int4*)&Bt[(n0+row)*K + kt*32+ko];
    }
    __syncthreads();
    bf16x8 af[4], bfv[4];
    for(int m=0;m<4;m++) af[m]=*(const bf16x8*)&As[(wr*64+m*16+fr)*32 + fq*8];
    for(int n=0;n<4;n++) bfv[n]=*(const bf16x8*)&Bs[(wc*64+n*16+fr)*32 + fq*8];
    for(int m=0;m<4;m++)
      for(int n=0;n<4;n++)
        acc[m][n]=__builtin_amdgcn_mfma_f32_16x16x32_bf16(af[m],bfv[n],acc[m][n],0,0,0);
  }
  for(int n=0;n<4;n++){
    size_t colg = n0 + wc*64+n*16+fr;
    float bv = bias[colg];
    for(int m=0;m<4;m++){
      for(int r=0;r<4;r++){
        size_t rowg = m0 + wr*64+m*16+fq*4+r;
        float v = acc[m][n][r]+bv;
        if constexpr (MODE==0){
          Cmat[rowg*N + colg] = f2bf(v);
        } else if constexpr (MODE==1){
          size_t p = colg>>10, pc = colg&1023;
          planes[p*PS + rowg*HID + pc] = f2bf(v);
        } else {
          size_t p = colg>>10, pc = colg&1023;
          u16* dst = planes + (2+p)*PS + rowg*HID + pc;
          *dst = f2bf(v + bf2f(*dst));
        }
      }
    }
  }
}

// ---------------- flag-array grid barrier (64 blocks) ----------------
__device__ inline void grid_barrier(u32* flags, u32 target){
  __threadfence();
  __syncthreads();
  if(threadIdx.x==0)
    __hip_atomic_store(&flags[(size_t)blockIdx.x*32], target, __ATOMIC_RELEASE, __HIP_MEMORY_SCOPE_AGENT);
  if(threadIdx.x<64){
    while(__hip_atomic_load(&flags[(size_t)threadIdx.x*32], __ATOMIC_ACQUIRE, __HIP_MEMORY_SCOPE_AGENT) < target)
      __builtin_amdgcn_s_sleep(2);
  }
  __syncthreads();
  __threadfence();
}

// ---------------- persistent recurrent kernel: one layer, T steps, 2 barriers/step ----
// PLAIN launch (not cooperative): 64 blocks on 256 CUs are structurally
// co-resident (empty stream, occupancy >= 1 block/CU), which is all the
// flag-array barrier needs. Block cj owns cols [16cj,16cj+16); wave w owns
// batch rows [16w,16w+16). Wmh cols in VGPRs; stage-B weights stream from L2.
__launch_bounds__(256, 1)
__global__ void mlstm_rec(const u16* __restrict__ xmi_p, const u16* __restrict__ xhi_p,
   const u16* __restrict__ xgi_p, const u16* __restrict__ xgo_p, const u16* __restrict__ xgf_p,
   const u16* __restrict__ Wmh_t, const u16* __restrict__ Whh_t, const u16* __restrict__ WhhG_t,
   const float* __restrict__ bmh, const float* __restrict__ bhh,
   u16* h_buf, float* c_buf, u16* m_buf,
   u16* seq_bf, float* seq_f32, float* hn, float* cn, u32* flags, int is_first)
{
  const int tid=threadIdx.x, lane=tid&63, wave=tid>>6;
  const int cb = blockIdx.x*16;
  const int rowbase = wave*16;
  const int fr=lane&15, fq=lane>>4;
  const int col = cb+fr;
  const u32 a_off = (u32)(rowbase+fr)*HID + fq*8;     // activation fragment base (u16 units)
  const size_t w_off = (size_t)col*HID + fq*8;        // weight fragment base (u16 units)

  // ---- Wmh fragments into VGPRs (statically indexed)
  bf16x8 wmh[32];
  #pragma unroll
  for(int kt=0;kt<32;kt++)
    wmh[kt] = *(const bf16x8*)(Wmh_t + w_off + kt*32);

  float c_reg[4], h4[4];
  if(is_first){ for(int r=0;r<4;r++) c_reg[r]=0.f; }
  else { for(int r=0;r<4;r++) c_reg[r]=c_buf[(size_t)(rowbase+fq*4+r)*HID+col]; }
  for(int r=0;r<4;r++) h4[r]=0.f;

  const float bmh_c=bmh[col], bhh_c=bhh[col];
  u32 bar=0;

  // prologue: xp loads for t=0
  float xmi[4],xhi[4],xgi[4],xgo[4],xgf[4];
  #pragma unroll
  for(int r=0;r<4;r++){
    size_t idx = (size_t)(rowbase+fq*4+r)*HID + col;
    xmi[r]=bf2f(xmi_p[idx]); xhi[r]=bf2f(xhi_p[idx]);
    xgi[r]=bf2f(xgi_p[idx]); xgo[r]=bf2f(xgo_p[idx]); xgf[r]=bf2f(xgf_p[idx]);
  }

  for(int t=0;t<T_STEPS;t++){
    // ---- Stage A: m = xmi * (h @ Wmh + bmh)
    f32x4 a0={0.f,0.f,0.f,0.f}, a1={0.f,0.f,0.f,0.f};
    #pragma unroll
    for(int kt=0;kt<32;kt+=2){
      bf16x8 av0=*(const bf16x8*)(h_buf + a_off + kt*32);
      bf16x8 av1=*(const bf16x8*)(h_buf + a_off + kt*32+32);
      a0=__builtin_amdgcn_mfma_f32_16x16x32_bf16(av0,wmh[kt],a0,0,0,0);
      a1=__builtin_amdgcn_mfma_f32_16x16x32_bf16(av1,wmh[kt+1],a1,0,0,0);
    }
    #pragma unroll
    for(int r=0;r<4;r++){
      int row=rowbase+fq*4+r;
      m_buf[(size_t)row*HID+col]=f2bf(xmi[r]*(a0[r]+a1[r]+bmh_c));
    }
    bar++; grid_barrier(flags,bar);

    // ---- prefetch xp for t+1 (latency hides under stage B)
    float nmi[4],nhi[4],ngi[4],ngo[4],ngf[4];
    {
      size_t tb2 = (size_t)((t+1<T_STEPS)?(t+1):t)*BATCH*HID;
      #pragma unroll
      for(int r=0;r<4;r++){
        size_t idx = tb2 + (size_t)(rowbase+fq*4+r)*HID + col;
        nmi[r]=bf2f(xmi_p[idx]); nhi[r]=bf2f(xhi_p[idx]);
        ngi[r]=bf2f(xgi_p[idx]); ngo[r]=bf2f(xgo_p[idx]); ngf[r]=bf2f(xgf_p[idx]);
      }
    }

    // ---- Stage B: [g|i|o|f] = m @ [Whh|WhhG]; gates; state update
    f32x4 ag={0.f,0.f,0.f,0.f}, ai={0.f,0.f,0.f,0.f}, ao={0.f,0.f,0.f,0.f}, af={0.f,0.f,0.f,0.f};
    #pragma unroll 4
    for(int kt=0;kt<32;kt++){
      bf16x8 mv = *(const bf16x8*)(m_buf + a_off + kt*32);
      bf16x8 w0 = *(const bf16x8*)(Whh_t  + w_off + kt*32);
      bf16x8 w1 = *(const bf16x8*)(WhhG_t + w_off + kt*32);
      bf16x8 w2 = *(const bf16x8*)(WhhG_t + (size_t)HID*HID + w_off + kt*32);
      bf16x8 w3 = *(const bf16x8*)(WhhG_t + (size_t)2*HID*HID + w_off + kt*32);
      ag=__builtin_amdgcn_mfma_f32_16x16x32_bf16(mv,w0,ag,0,0,0);
      ai=__builtin_amdgcn_mfma_f32_16x16x32_bf16(mv,w1,ai,0,0,0);
      ao=__builtin_amdgcn_mfma_f32_16x16x32_bf16(mv,w2,ao,0,0,0);
      af=__builtin_amdgcn_mfma_f32_16x16x32_bf16(mv,w3,af,0,0,0);
    }
    const size_t tb = (size_t)t*BATCH*HID;
    #pragma unroll
    for(int r=0;r<4;r++){
      int row=rowbase+fq*4+r;
      float g  = ag[r]+bhh_c+xhi[r];
      float iv = sigm(ai[r]+xgi[r]);
      float ov = sigm(ao[r]+xgo[r]);
      float fv = sigm(af[r]+xgf[r]);
      c_reg[r]=fv*c_reg[r]+iv*tanhf(g);
      h4[r]=tanhf(c_reg[r])*ov;
      h_buf[(size_t)row*HID+col]=f2bf(h4[r]);
      if(seq_bf) seq_bf[tb + (size_t)row*HID+col]=f2bf(h4[r]);
      else       seq_f32[tb + (size_t)row*HID+col]=h4[r];
    }
    #pragma unroll
    for(int r=0;r<4;r++){ xmi[r]=nmi[r]; xhi[r]=nhi[r]; xgi[r]=ngi[r]; xgo[r]=ngo[r]; xgf[r]=ngf[r]; }
    bar++; grid_barrier(flags,bar);
  }
  for(int r=0;r<4;r++){
    int row=rowbase+fq*4+r;
    hn[(size_t)row*HID+col]=h4[r];
    cn[(size_t)row*HID+col]=c_reg[r];
    if(is_first) c_buf[(size_t)row*HID+col]=c_reg[r];
  }
}

extern "C" void kernel_launch(void* const* d_in, const int* in_sizes, int n_in,
                              void* d_out, int out_size, void* d_ws, size_t ws_size,
                              hipStream_t stream){
  const float* x   = (const float*)d_in[0];
  const float* Wx  = (const float*)d_in[1];
  const float* bx  = (const float*)d_in[2];
  const float* Wmh = (const float*)d_in[3];
  const float* bmh = (const float*)d_in[4];
  const float* Whh = (const float*)d_in[5];
  const float* bhh = (const float*)d_in[6];
  const float* Wg  = (const float*)d_in[7];
  const float* bg  = (const float*)d_in[8];
  float* out = (float*)d_out;
  char* ws = (char*)d_ws;

  const size_t TB = (size_t)T_STEPS*BATCH;
  const size_t PS = TB*HID;           // plane stride (elements)

  size_t off=0;
  auto alloc=[&](size_t b){ size_t o=off; off += (b+255)&~(size_t)255; return o; };
  size_t planes_off = alloc(5*PS*2);                        // 335.5 MB
  size_t seq_off  = alloc(PS*2);                            // 67 MB
  size_t wx_off   = alloc((size_t)NLAYER*5*HID*DIM*2);      // 21 MB
  size_t wmh_off  = alloc((size_t)NLAYER*HID*HID*2);
  size_t whh_off  = alloc((size_t)NLAYER*HID*HID*2);
  size_t wg_off   = alloc((size_t)NLAYER*3*HID*HID*2);
  size_t whhp_off = alloc((size_t)NLAYER*HID*HID*2);        // Whh plain bf16
  size_t whhg_off = alloc((size_t)3*HID*HID*2);             // WhhG_t (per-layer reuse)
  size_t bias2_off= alloc((size_t)3*HID*4);
  size_t zeros_off= alloc(4096);
  size_t h_off    = alloc((size_t)BATCH*HID*2);
  size_t m_off    = alloc((size_t)BATCH*HID*2);
  size_t c_off    = alloc((size_t)BATCH*HID*4);
  size_t flag_off = alloc(16384);
  (void)ws_size;

  u16* planes_p = (u16*)(ws+planes_off);
  u16* seq_p  = (u16*)(ws+seq_off);
  u16* wx_p   = (u16*)(ws+wx_off);
  u16* wmh_p  = (u16*)(ws+wmh_off);
  u16* whh_p  = (u16*)(ws+whh_off);
  u16* wg_p   = (u16*)(ws+wg_off);
  u16* whhpl_p= (u16*)(ws+whhp_off);
  u16* whhg_p = (u16*)(ws+whhg_off);
  float* bias2_p = (float*)(ws+bias2_off);
  float* zeros_p = (float*)(ws+zeros_off);
  u16* h_p  = (u16*)(ws+h_off);
  u16* m_p  = (u16*)(ws+m_off);
  float* c_p= (float*)(ws+c_off);
  u32* flags_p= (u32*)(ws+flag_off);

  hipMemsetAsync(h_p, 0, (size_t)BATCH*HID*2, stream);
  hipMemsetAsync(flags_p, 0, 16384, stream);
  hipMemsetAsync(zeros_p, 0, 4096, stream);

  cast_f2bf<<<4096,256,0,stream>>>(x, seq_p, T_STEPS*BATCH*DIM/4);
  cast_f2bf<<<2048,256,0,stream>>>(Whh, whhpl_p, NLAYER*HID*HID/4);

  for(int l=0;l<NLAYER;l++){
    transpose_cast<<<dim3(5*HID/32, DIM/32), dim3(32,8),0,stream>>>(
        Wx + (size_t)l*DIM*5*HID, wx_p + (size_t)l*5*HID*DIM, DIM, 5*HID);
    transpose_cast<<<dim3(HID/32, HID/32), dim3(32,8),0,stream>>>(
        Wmh + (size_t)l*HID*HID, wmh_p + (size_t)l*HID*HID, HID, HID);
    transpose_cast<<<dim3(HID/32, HID/32), dim3(32,8),0,stream>>>(
        Whh + (size_t)l*HID*HID, whh_p + (size_t)l*HID*HID, HID, HID);
    transpose_cast<<<dim3(3*HID/32, HID/32), dim3(32,8),0,stream>>>(
        Wg + (size_t)l*HID*3*HID, wg_p + (size_t)l*3*HID*HID, HID, 3*HID);
  }

  float* seq_out_f32 = out;                                  // [T,B,H]
  float* hn_out = out + PS;                                  // [L,B,H]
  float* cn_out = hn_out + (size_t)NLAYER*BATCH*HID;         // [L,B,H]

  for(int l=0;l<NLAYER;l++){
    const u16* wg_l = wg_p + (size_t)l*3*HID*HID;
    // bias2 = bhh @ Wg + bg
    bias2_kernel<<<768,256,0,stream>>>(wg_l, bhh + (size_t)l*HID, bg + (size_t)l*3*HID, bias2_p);
    // WhhG_t[3H][H]: WhhG_t[n][k] = sum_j Wg[j][n]*Whh[k][j]  ((m@Whh)@Wg == m@WhhG)
    gemm_bt<0><<<dim3(HID/128, 3*HID/128),256,0,stream>>>(
        wg_l, whhpl_p + (size_t)l*HID*HID, zeros_p, whhg_p,
        3*HID, HID, HID, nullptr, 0);
    // xp planes: [mi|hi|ii|oi|fi]
    gemm_bt<1><<<dim3(5*HID/128, (int)(TB/128)),256,0,stream>>>(
        seq_p, wx_p+(size_t)l*5*HID*DIM, bx + (size_t)l*5*HID, nullptr,
        (int)TB, 5*HID, DIM, planes_p, PS);
    // XG fuse: planes[2..4] += hi@Wg + bias2
    gemm_bt<2><<<dim3(3*HID/128, (int)(TB/128)),256,0,stream>>>(
        planes_p + PS, wg_l, bias2_p, nullptr,
        (int)TB, 3*HID, HID, planes_p, PS);

    const u16* xmi_c = planes_p;
    const u16* xhi_c = planes_p + PS;
    const u16* xgi_c = planes_p + 2*PS;
    const u16* xgo_c = planes_p + 3*PS;
    const u16* xgf_c = planes_p + 4*PS;
    const u16* wm_c = wmh_p + (size_t)l*HID*HID;
    const u16* wh_c = whh_p + (size_t)l*HID*HID;
    const u16* wG_c = whhg_p;
    const float* bmh_l = bmh + (size_t)l*HID;
    const float* bhh_l = bhh + (size_t)l*HID;
    u16* seqbf = (l==0)? seq_p : (u16*)nullptr;
    float* seqf = (l==0)? (float*)nullptr : seq_out_f32;
    float* hn_l = hn_out + (size_t)l*BATCH*HID;
    float* cn_l = cn_out + (size_t)l*BATCH*HID;
    u32* flags_l = flags_p + (size_t)l*2048;
    int is_first = (l==0)?1:0;

    mlstm_rec<<<dim3(64), dim3(256), 0, stream>>>(
        xmi_c, xhi_c, xgi_c, xgo_c, xgf_c,
        wm_c, wh_c, wG_c,
        bmh_l, bhh_l,
        h_p, c_p, m_p,
        seqbf, seqf, hn_l, cn_l, flags_l, is_first);
  }
}